// Round 18
// baseline (216.136 us; speedup 1.0000x reference)
//
#include <hip/hip_runtime.h>

#define TINYF 1e-8f
#define NITER 50

typedef float v2f __attribute__((ext_vector_type(2)));
__device__ __forceinline__ v2f b2(float v) { v2f r; r.x = v; r.y = v; return r; }

__device__ __forceinline__ float bperm(int addr4, float v) {
    return __int_as_float(__builtin_amdgcn_ds_bpermute(addr4, __float_as_int(v)));
}
// lane i <- lane i-1 within 16-lane DPP row; 0 at row edge (= crop left edge)
__device__ __forceinline__ float dpp_shr1(float v) {
    return __int_as_float(__builtin_amdgcn_update_dpp(0, __float_as_int(v), 0x111, 0xf, 0xf, true));
}
// lane i <- lane i+1 within 16-lane DPP row; 0 at row edge (= crop right edge)
__device__ __forceinline__ float dpp_shl1(float v) {
    return __int_as_float(__builtin_amdgcn_update_dpp(0, __float_as_int(v), 0x101, 0xf, 0xf, true));
}

// full prep: s1 (|dx|=1 pairs) + s2 (|dx|=2 pairs) for this lane's 3 cols
#define PREPF(C0_, C1_, C2_) \
    L2 = dpp_shr1(C1_); L1 = dpp_shr1(C2_); R1 = dpp_shl1(C0_); R2 = dpp_shl1(C1_); \
    s1a = L1 + C1_; s1b = C0_ + C2_; s1c = C1_ + R1; \
    s2a = L2 + C2_; s2b = L1 + R1; s2c = C0_ + R2;
// s1-only prep (for |dy|=1 halo rows)
#define PREPS(C0_, C1_, C2_) \
    L1 = dpp_shr1(C2_); R1 = dpp_shl1(C0_); \
    s1a = L1 + C1_; s1b = C0_ + C2_; s1c = C1_ + R1;

// packed accumulate: pair P (acc rows 2P,2P+1), window row values X0..X2
#define PKC(P, X0_, X1_, X2_, KP) \
    A[P][0] += b2(X0_) * KP; \
    A[P][1] += b2(X1_) * KP; \
    A[P][2] += b2(X2_) * KP;
#define PKS1(P, KP) \
    A[P][0] += b2(s1a) * KP; \
    A[P][1] += b2(s1b) * KP; \
    A[P][2] += b2(s1c) * KP;
#define PKS2(P, KP) \
    A[P][0] += b2(s2a) * KP; \
    A[P][1] += b2(s2b) * KP; \
    A[P][2] += b2(s2c) * KP;

// EX layout (floats): [parity(2)][side(2)][row(2)][lane16][4]
__global__ void __launch_bounds__(128)
__attribute__((amdgpu_waves_per_eu(1, 2)))
sinkhorn_pk(const float* __restrict__ hm_gt,
            const float* __restrict__ hm_pred,
            const int* __restrict__ tops,
            float* __restrict__ out) {
    __shared__ __align__(16) float EX[2 * 512];
    __shared__ float sred[4];

    const int t = threadIdx.x;
    const int W = t >> 6;                  // wave 0: rows 0-23; wave 1: rows 24-47
    const int l = t & 63;
    const int b = l >> 4, c = l & 15;      // band (6 rows) x colgroup (3 cols)
    const bool btop = (b == 0), bbot = (b == 3);
    const bool xchg = (W == 0) ? bbot : btop;
    const int upA = ((l - 16) & 63) << 2;
    const int dnA = ((l + 16) & 63) << 2;

    const int blk = blockIdx.x;            // ((bi*8+rr)*5+cc)
    const int bi = blk / 40, rr = (blk / 5) % 8, cc = blk % 5;
    const int y0 = tops[(bi * 8 + rr) * 2 + 0];
    const int x0 = tops[(bi * 8 + rr) * 2 + 1];
    const float* srcA = hm_gt + (size_t)(bi * 5 + cc) * 25600;
    const float* srcB = hm_pred + (size_t)(bi * 5 + cc) * 25600;

    float* wp = EX + W * 256 + c * 4;
    const float* rp = EX + (1 - W) * 256 + c * 4;

    // ---- load own 6x3 tiles of both crops; block-reduce sums ----
    float va[6][3], vb[6][3];
    float sA = 0.f, sB = 0.f;
    const int rbase = y0 + 24 * W + 6 * b;
#pragma unroll
    for (int i = 0; i < 6; ++i) {
        const int g = (rbase + i) * 160 + x0 + 3 * c;
#pragma unroll
        for (int j = 0; j < 3; ++j) {
            const float A_ = srcA[g + j];
            const float B_ = srcB[g + j];
            va[i][j] = A_; vb[i][j] = B_;
            sA += A_; sB += B_;
        }
    }
#pragma unroll
    for (int o = 1; o < 64; o <<= 1) {
        sA += __shfl_xor(sA, o, 64);
        sB += __shfl_xor(sB, o, 64);
    }
    if (l == 0) { sred[W] = sA; sred[2 + W] = sB; }
    __syncthreads();
    sA = sred[0] + sred[1];
    sB = sred[2] + sred[3];
    const float nA = 1.0f / (sA + TINYF);
    const float nB = 1.0f / (sB + TINYF);
#pragma unroll
    for (int i = 0; i < 6; ++i)
#pragma unroll
        for (int j = 0; j < 3; ++j) { va[i][j] *= nA; vb[i][j] *= nB; }

    // Gibbs weights (same expressions as before -> same rounding)
    const float e10 = expf(-1.0f / 0.1f);
    const float e2  = expf(-sqrtf(2.0f) / 0.1f);
    const float e20 = expf(-2.0f / 0.1f);

    float xu[6][3], xv[6][3];
    v2f A[3][3];
    const float u0 = 1.0f / 2304.0f;
#pragma unroll
    for (int i = 0; i < 6; ++i)
#pragma unroll
        for (int j = 0; j < 3; ++j) xu[i][j] = u0;

    if (xchg) {
        *(float4*)(wp)      = make_float4(u0, u0, u0, 0.f);
        *(float4*)(wp + 64) = make_float4(u0, u0, u0, 0.f);
    }
    __syncthreads();

    // 13-tap conv, packed over row pairs. Per-acc-row contribution order matches
    // R16 (w ascending, then hB,hA,hC,hD); zero-half fma terms are exact no-ops.
    auto conv = [&](const float (&x)[6][3], int poffR,
                    float K00, float K01, float K02,
                    float K10, float K11, float K20) {
        // packed weight constants (loop-invariant; LICM hoists)
        const v2f cA = {K00, K10}, cB = {K10, K00}, cC = {K20, K10};
        const v2f cD = {0.f, K20}, cE = {K20, 0.f}, cF = {K10, K20};
        const v2f s1A = {K01, K11}, s1B = {K11, K01};
        const v2f s1C = {0.f, K11}, s1D = {K11, 0.f};
        const v2f s2A = {K02, 0.f}, s2B = {0.f, K02};

        float4 q0 = make_float4(0.f, 0.f, 0.f, 0.f), q1 = q0;
        if (xchg) {
            q0 = *(const float4*)(rp + poffR);
            q1 = *(const float4*)(rp + poffR + 64);
        }
        float tA[3], tB[3], tC[3], tD[3];
#pragma unroll
        for (int j = 0; j < 3; ++j) {
            tA[j] = bperm(upA, x[4][j]);   // row -2 candidate
            tB[j] = bperm(upA, x[5][j]);   // row -1
            tC[j] = bperm(dnA, x[0][j]);   // row  6
            tD[j] = bperm(dnA, x[1][j]);   // row  7
        }
#pragma unroll
        for (int p = 0; p < 3; ++p)
#pragma unroll
            for (int j = 0; j < 3; ++j) A[p][j] = b2(0.f);

        float L1, L2, R1, R2, s1a, s1b, s1c, s2a, s2b, s2c;
        // own rows, w ascending
        PREPF(x[0][0], x[0][1], x[0][2])                       // w=0
        PKC(0, x[0][0], x[0][1], x[0][2], cA) PKS1(0, s1A) PKS2(0, s2A)
        PKC(1, x[0][0], x[0][1], x[0][2], cE)
        PREPF(x[1][0], x[1][1], x[1][2])                       // w=1
        PKC(0, x[1][0], x[1][1], x[1][2], cB) PKS1(0, s1B) PKS2(0, s2B)
        PKC(1, x[1][0], x[1][1], x[1][2], cF) PKS1(1, s1D)
        PREPF(x[2][0], x[2][1], x[2][2])                       // w=2
        PKC(0, x[2][0], x[2][1], x[2][2], cC) PKS1(0, s1C)
        PKC(1, x[2][0], x[2][1], x[2][2], cA) PKS1(1, s1A) PKS2(1, s2A)
        PKC(2, x[2][0], x[2][1], x[2][2], cE)
        PREPF(x[3][0], x[3][1], x[3][2])                       // w=3
        PKC(0, x[3][0], x[3][1], x[3][2], cD)
        PKC(1, x[3][0], x[3][1], x[3][2], cB) PKS1(1, s1B) PKS2(1, s2B)
        PKC(2, x[3][0], x[3][1], x[3][2], cF) PKS1(2, s1D)
        PREPF(x[4][0], x[4][1], x[4][2])                       // w=4
        PKC(1, x[4][0], x[4][1], x[4][2], cC) PKS1(1, s1C)
        PKC(2, x[4][0], x[4][1], x[4][2], cA) PKS1(2, s1A) PKS2(2, s2A)
        PREPF(x[5][0], x[5][1], x[5][2])                       // w=5
        PKC(1, x[5][0], x[5][1], x[5][2], cD)
        PKC(2, x[5][0], x[5][1], x[5][2], cB) PKS1(2, s1B) PKS2(2, s2B)

        // resolve halos
        float hA[3], hB[3], hC[3], hD[3];
        const float qv0[3] = {q0.x, q0.y, q0.z};
        const float qv1[3] = {q1.x, q1.y, q1.z};
#pragma unroll
        for (int j = 0; j < 3; ++j) {
            if (W == 0) {
                hA[j] = btop ? 0.f : tA[j];
                hB[j] = btop ? 0.f : tB[j];
                hC[j] = bbot ? qv0[j] : tC[j];
                hD[j] = bbot ? qv1[j] : tD[j];
            } else {
                hA[j] = btop ? qv0[j] : tA[j];
                hB[j] = btop ? qv1[j] : tB[j];
                hC[j] = bbot ? 0.f : tC[j];
                hD[j] = bbot ? 0.f : tD[j];
            }
        }
        PREPS(hB[0], hB[1], hB[2])          // row -1 -> pair 0 (dy 1,2)
        PKC(0, hB[0], hB[1], hB[2], cF) PKS1(0, s1D)
        PKC(0, hA[0], hA[1], hA[2], cE)     // row -2 -> pair 0 (dy 2,3)
        PREPS(hC[0], hC[1], hC[2])          // row 6 -> pair 2 (dy 2,1)
        PKC(2, hC[0], hC[1], hC[2], cC) PKS1(2, s1C)
        PKC(2, hD[0], hD[1], hD[2], cD)     // row 7 -> pair 2 (dy 3,2)
    };

    auto publish = [&](const float (&y)[6][3], int poffW) {
        if (xchg) {
            const int r0 = (W == 0) ? 4 : 0;
            *(float4*)(wp + poffW)      = make_float4(y[r0][0], y[r0][1], y[r0][2], 0.f);
            *(float4*)(wp + poffW + 64) = make_float4(y[r0+1][0], y[r0+1][1], y[r0+1][2], 0.f);
        }
        __syncthreads();
    };

    // ---- Sinkhorn iterations: 1 barrier per half-iteration on a 2-wave block ----
#pragma unroll 1
    for (int it = 0; it < NITER; ++it) {
        conv(xu, 0, 1.0f, e10, e20, e10, e2, e20);
#pragma unroll
        for (int i = 0; i < 6; ++i)
#pragma unroll
            for (int j = 0; j < 3; ++j) {
                const float av = (i & 1) ? A[i >> 1][j].y : A[i >> 1][j].x;
                xv[i][j] = vb[i][j] * __builtin_amdgcn_rcpf(av + TINYF);
            }
        publish(xv, 512);

        conv(xv, 512, 1.0f, e10, e20, e10, e2, e20);
#pragma unroll
        for (int i = 0; i < 6; ++i)
#pragma unroll
            for (int j = 0; j < 3; ++j) {
                const float av = (i & 1) ? A[i >> 1][j].y : A[i >> 1][j].x;
                xu[i][j] = va[i][j] * __builtin_amdgcn_rcpf(av + TINYF);
            }
        publish(xu, 0);
    }

    // ---- loss: (u @ M) . v, M = K .* dist (center 0; e5/e8 taps dropped) ----
    const float s2f = sqrtf(2.0f);
    const float m01 = e10, m02 = e20 * 2.0f, m11 = e2 * s2f;
    conv(xu, 0, 0.0f, m01, m02, m01, m11, m02);
    float lsum = 0.f;
#pragma unroll
    for (int i = 0; i < 6; ++i)
#pragma unroll
        for (int j = 0; j < 3; ++j) {
            const float av = (i & 1) ? A[i >> 1][j].y : A[i >> 1][j].x;
            lsum += av * xv[i][j];
        }

#pragma unroll
    for (int o = 1; o < 64; o <<= 1) lsum += __shfl_xor(lsum, o, 64);
    if (l == 0) sred[W] = lsum;
    __syncthreads();
    if (t == 0) atomicAdd(out, sred[0] + sred[1]);
}

extern "C" void kernel_launch(void* const* d_in, const int* in_sizes, int n_in,
                              void* d_out, int out_size, void* d_ws, size_t ws_size,
                              hipStream_t stream) {
    (void)in_sizes; (void)n_in; (void)out_size; (void)d_ws; (void)ws_size;
    const float* hm_gt = (const float*)d_in[0];
    const float* hm_pred = (const float*)d_in[1];
    const int* tops = (const int*)d_in[2];
    float* out = (float*)d_out;

    hipMemsetAsync(out, 0, sizeof(float), stream);
    sinkhorn_pk<<<dim3(640), dim3(128), 0, stream>>>(hm_gt, hm_pred, tops, out);
}

// Round 20
// 183.608 us; speedup vs baseline: 1.1772x; 1.1772x over previous
//
#include <hip/hip_runtime.h>

#define TINYF 1e-8f
#define NITER 50

__device__ __forceinline__ float bperm(int addr4, float v) {
    return __int_as_float(__builtin_amdgcn_ds_bpermute(addr4, __float_as_int(v)));
}
// lane i <- lane i-1 within 16-lane DPP row; 0 at row edge (= crop left edge)
__device__ __forceinline__ float dpp_shr1(float v) {
    return __int_as_float(__builtin_amdgcn_update_dpp(0, __float_as_int(v), 0x111, 0xf, 0xf, true));
}
// lane i <- lane i+1 within 16-lane DPP row; 0 at row edge (= crop right edge)
__device__ __forceinline__ float dpp_shl1(float v) {
    return __int_as_float(__builtin_amdgcn_update_dpp(0, __float_as_int(v), 0x101, 0xf, 0xf, true));
}

// full prep: s1 (|dx|=1 pairs) + s2 (|dx|=2 pairs) for this lane's 3 cols
#define PREPF(C0_, C1_, C2_) \
    L2 = dpp_shr1(C1_); L1 = dpp_shr1(C2_); R1 = dpp_shl1(C0_); R2 = dpp_shl1(C1_); \
    s1a = L1 + C1_; s1b = C0_ + C2_; s1c = C1_ + R1; \
    s2a = L2 + C2_; s2b = L1 + R1; s2c = C0_ + R2;
// s1-only prep (for |dy|=1 halo rows)
#define PREPS(C0_, C1_, C2_) \
    L1 = dpp_shr1(C2_); R1 = dpp_shl1(C0_); \
    s1a = L1 + C1_; s1b = C0_ + C2_; s1c = C1_ + R1;
// dy=0 row: center + |dx|=1 + |dx|=2   (I-variant: first touch; acc=0+t == t)
#define AT0(I, C0_, C1_, C2_, KA, KB, KC) \
    acc[I][0] += KA * C0_ + KB * s1a + KC * s2a; \
    acc[I][1] += KA * C1_ + KB * s1b + KC * s2b; \
    acc[I][2] += KA * C2_ + KB * s1c + KC * s2c;
#define AT0I(I, C0_, C1_, C2_, KA, KB, KC) \
    acc[I][0] = KA * C0_ + KB * s1a + KC * s2a; \
    acc[I][1] = KA * C1_ + KB * s1b + KC * s2b; \
    acc[I][2] = KA * C2_ + KB * s1c + KC * s2c;
// |dy|=1 row: center + |dx|=1 (e5 corner dropped)
#define AT1(I, C0_, C1_, C2_, KA, KB) \
    acc[I][0] += KA * C0_ + KB * s1a; \
    acc[I][1] += KA * C1_ + KB * s1b; \
    acc[I][2] += KA * C2_ + KB * s1c;
#define AT1I(I, C0_, C1_, C2_, KA, KB) \
    acc[I][0] = KA * C0_ + KB * s1a; \
    acc[I][1] = KA * C1_ + KB * s1b; \
    acc[I][2] = KA * C2_ + KB * s1c;
// |dy|=2 row: center only (e5/e8 dropped)
#define AT2(I, C0_, C1_, C2_, KA) \
    acc[I][0] += KA * C0_; \
    acc[I][1] += KA * C1_; \
    acc[I][2] += KA * C2_;
#define AT2I(I, C0_, C1_, C2_, KA) \
    acc[I][0] = KA * C0_; \
    acc[I][1] = KA * C1_; \
    acc[I][2] = KA * C2_;

// EX layout (floats): [parity(2)][side(2)][row(2)][lane16][4]
// side0 = crop rows 22,23 (written by wave0 band3); side1 = rows 24,25 (wave1 band0).
__global__ void __launch_bounds__(128)
__attribute__((amdgpu_waves_per_eu(1, 2)))
sinkhorn_ft(const float* __restrict__ hm_gt,
            const float* __restrict__ hm_pred,
            const int* __restrict__ tops,
            float* __restrict__ out) {
    __shared__ __align__(16) float EX[2 * 512];
    __shared__ float sred[4];

    const int t = threadIdx.x;
    const int W = t >> 6;                  // wave 0: rows 0-23; wave 1: rows 24-47
    const int l = t & 63;
    const int b = l >> 4, c = l & 15;      // band (6 rows) x colgroup (3 cols)
    const bool btop = (b == 0), bbot = (b == 3);
    const bool xchg = (W == 0) ? bbot : btop;   // lanes on the inter-wave boundary
    const int upA = ((l - 16) & 63) << 2;
    const int dnA = ((l + 16) & 63) << 2;

    const int blk = blockIdx.x;            // ((bi*8+rr)*5+cc)
    const int bi = blk / 40, rr = (blk / 5) % 8, cc = blk % 5;
    const int y0 = tops[(bi * 8 + rr) * 2 + 0];
    const int x0 = tops[(bi * 8 + rr) * 2 + 1];
    const float* srcA = hm_gt + (size_t)(bi * 5 + cc) * 25600;
    const float* srcB = hm_pred + (size_t)(bi * 5 + cc) * 25600;

    // exchange pointers (parity adds +512 floats)
    float* wp = EX + W * 256 + c * 4;           // own side
    const float* rp = EX + (1 - W) * 256 + c * 4;

    // ---- load own 6x3 tiles of both crops; block-reduce sums ----
    float va[6][3], vb[6][3];
    float sA = 0.f, sB = 0.f;
    const int rbase = y0 + 24 * W + 6 * b;
#pragma unroll
    for (int i = 0; i < 6; ++i) {
        const int g = (rbase + i) * 160 + x0 + 3 * c;
#pragma unroll
        for (int j = 0; j < 3; ++j) {
            const float A = srcA[g + j];
            const float B = srcB[g + j];
            va[i][j] = A; vb[i][j] = B;
            sA += A; sB += B;
        }
    }
#pragma unroll
    for (int o = 1; o < 64; o <<= 1) {
        sA += __shfl_xor(sA, o, 64);
        sB += __shfl_xor(sB, o, 64);
    }
    if (l == 0) { sred[W] = sA; sred[2 + W] = sB; }
    __syncthreads();
    sA = sred[0] + sred[1];
    sB = sred[2] + sred[3];
    const float nA = 1.0f / (sA + TINYF);
    const float nB = 1.0f / (sB + TINYF);
#pragma unroll
    for (int i = 0; i < 6; ++i)
#pragma unroll
        for (int j = 0; j < 3; ++j) { va[i][j] *= nA; vb[i][j] *= nB; }

    // Gibbs weights (same expressions as before -> same rounding)
    const float e10 = expf(-1.0f / 0.1f);
    const float e2  = expf(-sqrtf(2.0f) / 0.1f);
    const float e20 = expf(-2.0f / 0.1f);

    float xu[6][3], xv[6][3], acc[6][3];
    const float u0 = 1.0f / 2304.0f;
#pragma unroll
    for (int i = 0; i < 6; ++i)
#pragma unroll
        for (int j = 0; j < 3; ++j) xu[i][j] = u0;

    // publish u0 boundary rows into parity-0 buffer
    if (xchg) {
        *(float4*)(wp)      = make_float4(u0, u0, u0, 0.f);
        *(float4*)(wp + 64) = make_float4(u0, u0, u0, 0.f);
    }
    __syncthreads();

    // 13-tap conv (center, 4x e10, 4x e2, 4x e20): vertical halos intra-wave via
    // bperm; inter-wave boundary via EX (parity poffR); zeros at crop top/bottom.
    // Own rows w ascending; first touches (= R16's first contributions):
    // acc0/1/2 @ w=0, acc3 @ w=1, acc4 @ w=2, acc5 @ w=3.
    auto conv = [&](const float (&x)[6][3], int poffR,
                    float K00, float K01, float K02,
                    float K10, float K11, float K20) {
        float4 q0 = make_float4(0.f, 0.f, 0.f, 0.f), q1 = q0;
        if (xchg) {
            q0 = *(const float4*)(rp + poffR);
            q1 = *(const float4*)(rp + poffR + 64);
        }
        float tA[3], tB[3], tC[3], tD[3];
#pragma unroll
        for (int j = 0; j < 3; ++j) {
            tA[j] = bperm(upA, x[4][j]);   // row -2 candidate
            tB[j] = bperm(upA, x[5][j]);   // row -1
            tC[j] = bperm(dnA, x[0][j]);   // row  6
            tD[j] = bperm(dnA, x[1][j]);   // row  7
        }

        float L1, L2, R1, R2, s1a, s1b, s1c, s2a, s2b, s2c;
        // own rows first (no DS dependence -> hides bperm/LDS latency)
        PREPF(x[0][0], x[0][1], x[0][2])                        // w=0
        AT0I(0, x[0][0], x[0][1], x[0][2], K00, K01, K02)
        AT1I(1, x[0][0], x[0][1], x[0][2], K10, K11)
        AT2I(2, x[0][0], x[0][1], x[0][2], K20)
        PREPF(x[1][0], x[1][1], x[1][2])                        // w=1
        AT1(0, x[1][0], x[1][1], x[1][2], K10, K11)
        AT0(1, x[1][0], x[1][1], x[1][2], K00, K01, K02)
        AT1(2, x[1][0], x[1][1], x[1][2], K10, K11)
        AT2I(3, x[1][0], x[1][1], x[1][2], K20)
        PREPF(x[2][0], x[2][1], x[2][2])                        // w=2
        AT2(0, x[2][0], x[2][1], x[2][2], K20)
        AT1(1, x[2][0], x[2][1], x[2][2], K10, K11)
        AT0(2, x[2][0], x[2][1], x[2][2], K00, K01, K02)
        AT1(3, x[2][0], x[2][1], x[2][2], K10, K11)
        AT2I(4, x[2][0], x[2][1], x[2][2], K20)
        PREPF(x[3][0], x[3][1], x[3][2])                        // w=3
        AT2(1, x[3][0], x[3][1], x[3][2], K20)
        AT1(2, x[3][0], x[3][1], x[3][2], K10, K11)
        AT0(3, x[3][0], x[3][1], x[3][2], K00, K01, K02)
        AT1(4, x[3][0], x[3][1], x[3][2], K10, K11)
        AT2I(5, x[3][0], x[3][1], x[3][2], K20)
        PREPF(x[4][0], x[4][1], x[4][2])                        // w=4
        AT2(2, x[4][0], x[4][1], x[4][2], K20)
        AT1(3, x[4][0], x[4][1], x[4][2], K10, K11)
        AT0(4, x[4][0], x[4][1], x[4][2], K00, K01, K02)
        AT1(5, x[4][0], x[4][1], x[4][2], K10, K11)
        PREPF(x[5][0], x[5][1], x[5][2])                        // w=5
        AT2(3, x[5][0], x[5][1], x[5][2], K20)
        AT1(4, x[5][0], x[5][1], x[5][2], K10, K11)
        AT0(5, x[5][0], x[5][1], x[5][2], K00, K01, K02)

        // resolve halos
        float hA[3], hB[3], hC[3], hD[3];
        const float qv0[3] = {q0.x, q0.y, q0.z};
        const float qv1[3] = {q1.x, q1.y, q1.z};
#pragma unroll
        for (int j = 0; j < 3; ++j) {
            if (W == 0) {
                hA[j] = btop ? 0.f : tA[j];
                hB[j] = btop ? 0.f : tB[j];
                hC[j] = bbot ? qv0[j] : tC[j];
                hD[j] = bbot ? qv1[j] : tD[j];
            } else {
                hA[j] = btop ? qv0[j] : tA[j];
                hB[j] = btop ? qv1[j] : tB[j];
                hC[j] = bbot ? 0.f : tC[j];
                hD[j] = bbot ? 0.f : tD[j];
            }
        }
        // halo-row contributions (hA/hD: center tap only -> no DPP prep)
        PREPS(hB[0], hB[1], hB[2])          // row -1
        AT1(0, hB[0], hB[1], hB[2], K10, K11)
        AT2(1, hB[0], hB[1], hB[2], K20)
        AT2(0, hA[0], hA[1], hA[2], K20)    // row -2
        PREPS(hC[0], hC[1], hC[2])          // row 6
        AT2(4, hC[0], hC[1], hC[2], K20)
        AT1(5, hC[0], hC[1], hC[2], K10, K11)
        AT2(5, hD[0], hD[1], hD[2], K20)    // row 7
    };

    // publish boundary rows of field y into parity buffer poffW, then sync
    auto publish = [&](const float (&y)[6][3], int poffW) {
        if (xchg) {
            const int r0 = (W == 0) ? 4 : 0;
            *(float4*)(wp + poffW)      = make_float4(y[r0][0], y[r0][1], y[r0][2], 0.f);
            *(float4*)(wp + poffW + 64) = make_float4(y[r0+1][0], y[r0+1][1], y[r0+1][2], 0.f);
        }
        __syncthreads();
    };

    // ---- Sinkhorn iterations: 1 barrier per half-iteration on a 2-wave block ----
#pragma unroll 1
    for (int it = 0; it < NITER; ++it) {
        conv(xu, 0, 1.0f, e10, e20, e10, e2, e20);
#pragma unroll
        for (int i = 0; i < 6; ++i)
#pragma unroll
            for (int j = 0; j < 3; ++j)
                xv[i][j] = vb[i][j] * __builtin_amdgcn_rcpf(acc[i][j] + TINYF);
        publish(xv, 512);

        conv(xv, 512, 1.0f, e10, e20, e10, e2, e20);
#pragma unroll
        for (int i = 0; i < 6; ++i)
#pragma unroll
            for (int j = 0; j < 3; ++j)
                xu[i][j] = va[i][j] * __builtin_amdgcn_rcpf(acc[i][j] + TINYF);
        publish(xu, 0);
    }

    // ---- loss: (u @ M) . v, M = K .* dist (center 0; e5/e8 taps dropped) ----
    const float s2f = sqrtf(2.0f);
    const float m01 = e10, m02 = e20 * 2.0f, m11 = e2 * s2f;
    conv(xu, 0, 0.0f, m01, m02, m01, m11, m02);
    float lsum = 0.f;
#pragma unroll
    for (int i = 0; i < 6; ++i)
#pragma unroll
        for (int j = 0; j < 3; ++j)
            lsum += acc[i][j] * xv[i][j];

#pragma unroll
    for (int o = 1; o < 64; o <<= 1) lsum += __shfl_xor(lsum, o, 64);
    if (l == 0) sred[W] = lsum;
    __syncthreads();
    if (t == 0) atomicAdd(out, sred[0] + sred[1]);
}

extern "C" void kernel_launch(void* const* d_in, const int* in_sizes, int n_in,
                              void* d_out, int out_size, void* d_ws, size_t ws_size,
                              hipStream_t stream) {
    (void)in_sizes; (void)n_in; (void)out_size; (void)d_ws; (void)ws_size;
    const float* hm_gt = (const float*)d_in[0];
    const float* hm_pred = (const float*)d_in[1];
    const int* tops = (const int*)d_in[2];
    float* out = (float*)d_out;

    hipMemsetAsync(out, 0, sizeof(float), stream);
    sinkhorn_ft<<<dim3(640), dim3(128), 0, stream>>>(hm_gt, hm_pred, tops, out);
}